// Round 2
// baseline (6077.383 us; speedup 1.0000x reference)
//
#include <hip/hip_runtime.h>
#include <hip/hip_bf16.h>

// Softsplat forward (summation splatting). B=4, C=64, H=512, W=512, fp32.
//
// R2: break the vmcnt in-order serialization. Each thread handles one source
// pixel x 16 channels: issue all 16 image loads (one waitcnt), compute 4
// bilinear taps once, then fire 64 non-returning atomicAdds with no
// intervening waits. Grid y = 4 channel-groups.

#define B_ 4
#define C_ 64
#define H_ 512
#define W_ 512
#define HW_ (H_ * W_)
#define CG 16   // channels per thread

__global__ __launch_bounds__(256) void zero_out(float4* __restrict__ out) {
    size_t i = (size_t)blockIdx.x * blockDim.x + threadIdx.x;
    out[i] = make_float4(0.f, 0.f, 0.f, 0.f);
}

__global__ __launch_bounds__(256) void softsplat_fwd(
    const float* __restrict__ image,   // [B, C, H, W]
    const float* __restrict__ flow,    // [B, 2, H, W]
    float* __restrict__ out)           // [B, C, H, W], pre-zeroed
{
    int p  = blockIdx.x * blockDim.x + threadIdx.x;  // source pixel id
    int cg = blockIdx.y;                             // channel group 0..3
    int b  = p >> 18;                                // HW = 2^18
    int yx = p & (HW_ - 1);
    int y  = yx >> 9;                                // W = 2^9
    int x  = yx & (W_ - 1);

    // Flow loads (issue early).
    float fxr = flow[(size_t)b * 2 * HW_ + yx];
    float fyr = flow[(size_t)b * 2 * HW_ + HW_ + yx];

    // Image loads: 16 back-to-back coalesced loads, single logical wait.
    const float* img = image + ((size_t)b * C_ + cg * CG) * HW_ + yx;
    float v[CG];
    #pragma unroll
    for (int i = 0; i < CG; ++i) v[i] = img[(size_t)i * HW_];

    float fx = fxr + (float)x;
    float fy = fyr + (float)y;
    float x0f = floorf(fx);
    float y0f = floorf(fy);
    int x0 = (int)x0f, y0 = (int)y0f;
    int x1 = x0 + 1,   y1 = y0 + 1;
    float wx1 = fx - x0f, wx0 = 1.0f - wx1;
    float wy1 = fy - y0f, wy0 = 1.0f - wy1;

    bool vx0 = (x0 >= 0) & (x0 < W_);
    bool vx1 = (x1 >= 0) & (x1 < W_);
    bool vy0 = (y0 >= 0) & (y0 < H_);
    bool vy1 = (y1 >= 0) & (y1 < H_);

    int   toff[4];
    float tw[4];
    bool  tv[4];
    toff[0] = y0 * W_ + x0; tw[0] = wx0 * wy0; tv[0] = vy0 & vx0;
    toff[1] = y0 * W_ + x1; tw[1] = wx1 * wy0; tv[1] = vy0 & vx1;
    toff[2] = y1 * W_ + x0; tw[2] = wx0 * wy1; tv[2] = vy1 & vx0;
    toff[3] = y1 * W_ + x1; tw[3] = wx1 * wy1; tv[3] = vy1 & vx1;

    float* ob = out + ((size_t)b * C_ + cg * CG) * HW_;

    // 64 fire-and-forget atomics, no waits in between.
    #pragma unroll
    for (int i = 0; i < CG; ++i) {
        float* oc = ob + (size_t)i * HW_;
        #pragma unroll
        for (int t = 0; t < 4; ++t) {
            if (tv[t]) atomicAdd(oc + toff[t], v[i] * tw[t]);
        }
    }
}

extern "C" void kernel_launch(void* const* d_in, const int* in_sizes, int n_in,
                              void* d_out, int out_size, void* d_ws, size_t ws_size,
                              hipStream_t stream) {
    const float* image = (const float*)d_in[0];
    const float* flow  = (const float*)d_in[1];
    float* out = (float*)d_out;

    // Zero d_out (poisoned 0xAA) with a float4 store kernel (~4x faster than
    // the observed hipMemsetAsync path).
    int n4 = out_size / 4;                       // 16,777,216 float4s
    zero_out<<<n4 / 256, 256, 0, stream>>>((float4*)out);

    int pixels = B_ * HW_;                       // 1,048,576
    dim3 grid(pixels / 256, C_ / CG);            // (4096, 4)
    softsplat_fwd<<<grid, dim3(256, 1, 1), 0, stream>>>(image, flow, out);
}